// Round 16
// baseline (227.322 us; speedup 1.0000x reference)
//
#include <hip/hip_runtime.h>
#include <hip/hip_bf16.h>

#define D 128
#define CHUNK 1024   // elements per scan block (256 thr x 4)
#define NXCD 8

typedef __attribute__((ext_vector_type(8))) short bf16x8;
typedef __attribute__((ext_vector_type(4))) float f32x4;

// ---- bf16 helpers (bit-level, RNE via __float2bfloat16) --------------------
__device__ inline float bflo(unsigned u) { return __uint_as_float(u << 16); }
__device__ inline float bfhi(unsigned u) { return __uint_as_float(u & 0xffff0000u); }
__device__ inline unsigned short f2bf(float f) {
    __hip_bfloat16 h = __float2bfloat16(f);
    return *reinterpret_cast<unsigned short*>(&h);
}
__device__ inline unsigned pack2bf(float lo, float hi) {
    return (unsigned)f2bf(lo) | ((unsigned)f2bf(hi) << 16);
}

// ---------------------------------------------------------------------------
// convert + hist, BLOCK-SPLIT fusion (independent phases share the GPU):
//  blocks [0, ncb): fp32->bf16 streaming convert of feat|W (BW-bound)
//  blocks [ncb, grid): per-edge rank-returning histogram (latency-bound)
// Unlike R11's per-thread interleave (VGPR=8, serialized), each path keeps
// its own loop -> own ILP; CU scheduler overlaps atomic latency with the
// convert stream. cnt[] is zeroed by a preceding memset (RMW'd here, then
// plain-read by scans: proven pattern).
// ---------------------------------------------------------------------------
__global__ __launch_bounds__(256) void convert_hist_kernel(
    const float* __restrict__ feat, unsigned short* __restrict__ featb, int n4f,
    const float* __restrict__ W, unsigned short* __restrict__ Wb, int n4w,
    const int* __restrict__ src, const int* __restrict__ dst,
    int* __restrict__ cnt, int* __restrict__ rankF, int* __restrict__ rankB,
    int E, int N, int ncb)
{
    if ((int)blockIdx.x < ncb) {
        int i = blockIdx.x * 256 + threadIdx.x;
        const int stride = ncb * 256;
        const int n4 = n4f + n4w;
        for (int j = i; j < n4; j += stride) {
            const float* x; unsigned short* y; int k;
            if (j < n4f) { x = feat; y = featb; k = j; }
            else         { x = W;    y = Wb;    k = j - n4f; }
            float4 v = *reinterpret_cast<const float4*>(&x[(size_t)k * 4]);
            uint2 o;
            o.x = pack2bf(v.x, v.y);
            o.y = pack2bf(v.z, v.w);
            *reinterpret_cast<uint2*>(&y[(size_t)k * 4]) = o;
        }
    } else {
        int i = (blockIdx.x - ncb) * 256 + threadIdx.x;
        const int stride = (gridDim.x - ncb) * 256;
        for (int e = i; e < E; e += stride) {
            rankF[e] = atomicAdd(&cnt[dst[e]], 1);
            rankB[e] = atomicAdd(&cnt[N + src[e]], 1);
        }
    }
}

// ---------------------------------------------------------------------------
// scan1: per-block (CHUNK=1024) sums of cnt into blk[] (R5-proven).
// ---------------------------------------------------------------------------
__global__ __launch_bounds__(256) void scan1_kernel(
    const int* __restrict__ cnt, int* __restrict__ blk, int n2)
{
    __shared__ int red[256];
    const int b = blockIdx.x, t = threadIdx.x;
    const int base = b * CHUNK + t * 4;
    int s = 0;
    if (base + 3 < n2) {
        int4 v = *reinterpret_cast<const int4*>(&cnt[base]);
        s = v.x + v.y + v.z + v.w;
    } else {
        for (int j = 0; j < 4; ++j) { int idx = base + j; if (idx < n2) s += cnt[idx]; }
    }
    red[t] = s; __syncthreads();
    for (int o = 128; o > 0; o >>= 1) { if (t < o) red[t] += red[t + o]; __syncthreads(); }
    if (t == 0) blk[b] = red[0];
}

// ---------------------------------------------------------------------------
// scan3 (scan2 folded in): self-scan of NB block sums in LDS, then chunk
// exclusive prefix -> off[] (IMMUTABLE afterwards). (R11/R12-proven.)
// ---------------------------------------------------------------------------
__global__ __launch_bounds__(256) void scan3_kernel(
    const int* __restrict__ cnt, const int* __restrict__ blk,
    int* __restrict__ off, int n2, int total, int NB)
{
    __shared__ int sh[256];
    __shared__ int bs[256];
    const int b = blockIdx.x, t = threadIdx.x;

    bs[t] = (t < NB) ? blk[t] : 0;
    __syncthreads();
    for (int o = 1; o < 256; o <<= 1) {
        int v = (t >= o) ? bs[t - o] : 0;
        __syncthreads();
        bs[t] += v;
        __syncthreads();
    }
    const int blkpref = (b > 0) ? bs[b - 1] : 0;

    const int base = b * CHUNK + t * 4;
    int v[4]; int s = 0;
    for (int j = 0; j < 4; ++j) { int idx = base + j; v[j] = (idx < n2) ? cnt[idx] : 0; s += v[j]; }
    sh[t] = s; __syncthreads();
    for (int o = 1; o < 256; o <<= 1) {
        int x = (t >= o) ? sh[t - o] : 0;
        __syncthreads();
        sh[t] += x;
        __syncthreads();
    }
    int excl = blkpref + ((t > 0) ? sh[t - 1] : 0);
    for (int j = 0; j < 4; ++j) {
        int idx = base + j;
        if (idx < n2) off[idx] = excl;
        excl += v[j];
    }
    if (b == 0 && t == 0) off[n2] = total;
}

// ---------------------------------------------------------------------------
// Scatter edge ids: ATOMIC-FREE (slot = off[seg] + rank), node-range
// partitioned for XCD write locality (R6/R11-proven).
// ---------------------------------------------------------------------------
__global__ __launch_bounds__(256) void scatter_ids_kernel(
    const int* __restrict__ src, const int* __restrict__ dst,
    const int* __restrict__ off,
    const int* __restrict__ rankF, const int* __restrict__ rankB,
    int* __restrict__ csr, int E, int N, int npr)
{
    const int grp = blockIdx.x & (NXCD - 1);
    const int bIn = blockIdx.x >> 3;
    const int nbk = gridDim.x >> 3;
    const int lo = grp * npr;
    const int hi = lo + npr;

    int i = bIn * 256 + threadIdx.x;
    const int stride = nbk * 256;
    for (int e = i; e < E; e += stride) {
        const int s = src[e];
        const int d = dst[e];
        if (d >= lo && d < hi) {
            csr[off[d] + rankF[e]] = s;
        }
        if (s >= lo && s < hi) {
            csr[off[N + s] + rankB[e]] = d;
        }
    }
}

// ---------------------------------------------------------------------------
// gather means (R12-proven row-major form, plain csr loads — nt hurt in the
// R15 A/B: 87us/271MB vs 81us/259MB). 16 lanes per segment; lane l owns bf16
// columns [8l, 8l+8). Bounds from IMMUTABLE off. Unroll-4.
// ---------------------------------------------------------------------------
__global__ __launch_bounds__(256) void gather_mean_kernel(
    const unsigned short* __restrict__ featb, const int* __restrict__ off,
    const int* __restrict__ csr, unsigned short* __restrict__ meanb, int n2)
{
    const int tid = blockIdx.x * 256 + threadIdx.x;
    const int seg = tid >> 4;
    const int l = tid & 15;
    if (seg >= n2) return;

    const int beg = off[seg], end = off[seg + 1];
    float a0=0,a1=0,a2=0,a3=0,a4=0,a5=0,a6=0,a7=0;

    int e = beg;
    for (; e + 3 < end; e += 4) {
        const int n0 = csr[e], n1 = csr[e + 1], n2i = csr[e + 2], n3 = csr[e + 3];
        const uint4 v0 = *reinterpret_cast<const uint4*>(featb + (size_t)n0 * D + l * 8);
        const uint4 v1 = *reinterpret_cast<const uint4*>(featb + (size_t)n1 * D + l * 8);
        const uint4 v2 = *reinterpret_cast<const uint4*>(featb + (size_t)n2i * D + l * 8);
        const uint4 v3 = *reinterpret_cast<const uint4*>(featb + (size_t)n3 * D + l * 8);
        a0 += (bflo(v0.x) + bflo(v1.x)) + (bflo(v2.x) + bflo(v3.x));
        a1 += (bfhi(v0.x) + bfhi(v1.x)) + (bfhi(v2.x) + bfhi(v3.x));
        a2 += (bflo(v0.y) + bflo(v1.y)) + (bflo(v2.y) + bflo(v3.y));
        a3 += (bfhi(v0.y) + bfhi(v1.y)) + (bfhi(v2.y) + bfhi(v3.y));
        a4 += (bflo(v0.z) + bflo(v1.z)) + (bflo(v2.z) + bflo(v3.z));
        a5 += (bfhi(v0.z) + bfhi(v1.z)) + (bfhi(v2.z) + bfhi(v3.z));
        a6 += (bflo(v0.w) + bflo(v1.w)) + (bflo(v2.w) + bflo(v3.w));
        a7 += (bfhi(v0.w) + bfhi(v1.w)) + (bfhi(v2.w) + bfhi(v3.w));
    }
    for (; e < end; ++e) {
        const int n0 = csr[e];
        const uint4 v0 = *reinterpret_cast<const uint4*>(featb + (size_t)n0 * D + l * 8);
        a0 += bflo(v0.x); a1 += bfhi(v0.x);
        a2 += bflo(v0.y); a3 += bfhi(v0.y);
        a4 += bflo(v0.z); a5 += bfhi(v0.z);
        a6 += bflo(v0.w); a7 += bfhi(v0.w);
    }

    const int deg = end - beg;
    const float inv = 1.0f / (float)((deg > 1) ? deg : 1);
    uint4 o;
    o.x = pack2bf(a0 * inv, a1 * inv);
    o.y = pack2bf(a2 * inv, a3 * inv);
    o.z = pack2bf(a4 * inv, a5 * inv);
    o.w = pack2bf(a6 * inv, a7 * inv);
    *reinterpret_cast<uint4*>(meanb + (size_t)seg * D + l * 8) = o;
}

// ---------------------------------------------------------------------------
// bf16 MFMA GEMM v3 (R9/R12-proven, byte-identical). 512 thr, 128 rows/blk,
// K=128 LDS slabs double-buffered (3 barriers), XOR-swizzled, 12 A-frags
// register-prefetched, operand-swapped mfma(w,h), float4 epilogue.
// ---------------------------------------------------------------------------
__global__ __launch_bounds__(512) void mfma_gemm_kernel(
    const unsigned short* __restrict__ featb,
    const unsigned short* __restrict__ meanb,
    const unsigned short* __restrict__ Wb,      // [128][384] bf16
    float* __restrict__ out, int N)
{
    __shared__ unsigned short wlds[2][128 * 128];   // 2 x 32KB, swizzled [col][k]

    const int t = threadIdx.x;
    const int wv = t >> 6;          // 0..7
    const int lane = t & 63;
    const int r = lane & 15;
    const int q = lane >> 4;        // 0..3

    const int row0 = blockIdx.x * 128 + wv * 16;
    const int row = row0 + r;
    const int rowc = (row < N) ? row : (N - 1);

    // ---- prefetch all 12 A-fragments ----
    const unsigned short* h0 = featb + (size_t)rowc * D;
    const unsigned short* h1 = meanb + (size_t)rowc * D;
    const unsigned short* h2 = meanb + ((size_t)N + rowc) * D;
    bf16x8 af[12];
#pragma unroll
    for (int kk = 0; kk < 4; ++kk) {
        af[kk]     = *reinterpret_cast<const bf16x8*>(h0 + kk * 32 + q * 8);
        af[4 + kk] = *reinterpret_cast<const bf16x8*>(h1 + kk * 32 + q * 8);
        af[8 + kk] = *reinterpret_cast<const bf16x8*>(h2 + kk * 32 + q * 8);
    }

    // ---- W staging: thread t owns col sc, 4 x 16B sub-chunks ----
    const int sc = t >> 2;          // 0..127
    const int sq = t & 3;           // 0..3
    const char* wsrc = reinterpret_cast<const char*>(Wb) + (size_t)sc * 768;
    const int swz = (sc & 7) << 4;

    f32x4 acc[8];
#pragma unroll
    for (int n = 0; n < 8; ++n) acc[n] = (f32x4){0.f, 0.f, 0.f, 0.f};

    // prologue: stage slab 0 into buf 0
    {
        uint4 st[4];
#pragma unroll
        for (int j = 0; j < 4; ++j)
            st[j] = *reinterpret_cast<const uint4*>(wsrc + j * 64 + sq * 16);
        char* wb0 = reinterpret_cast<char*>(&wlds[0][0]) + sc * 256;
#pragma unroll
        for (int j = 0; j < 4; ++j)
            *reinterpret_cast<uint4*>(wb0 + ((j * 64 + sq * 16) ^ swz)) = st[j];
    }
    __syncthreads();

#pragma unroll
    for (int ci = 0; ci < 3; ++ci) {
        uint4 nx[4];
        if (ci < 2) {
#pragma unroll
            for (int j = 0; j < 4; ++j)
                nx[j] = *reinterpret_cast<const uint4*>(
                    wsrc + (ci + 1) * 256 + j * 64 + sq * 16);
        }

        const char* wl = reinterpret_cast<const char*>(&wlds[ci & 1][0]);
#pragma unroll
        for (int kk = 0; kk < 4; ++kk) {
            const bf16x8 bh = af[ci * 4 + kk];
#pragma unroll
            for (int n = 0; n < 8; ++n) {
                const int c = n * 16 + r;
                const bf16x8 aw = *reinterpret_cast<const bf16x8*>(
                    wl + c * 256 + ((kk * 64 + q * 16) ^ ((c & 7) << 4)));
                acc[n] = __builtin_amdgcn_mfma_f32_16x16x32_bf16(aw, bh, acc[n], 0, 0, 0);
            }
        }

        if (ci < 2) {
            char* wbn = reinterpret_cast<char*>(&wlds[(ci + 1) & 1][0]) + sc * 256;
#pragma unroll
            for (int j = 0; j < 4; ++j)
                *reinterpret_cast<uint4*>(wbn + ((j * 64 + sq * 16) ^ swz)) = nx[j];
            __syncthreads();
        }
    }

    // epilogue: lane (q,r) holds out[row0+r][n*16 + q*4 + i], i=0..3
    if (row < N) {
        float* orow = out + (size_t)row * D;
#pragma unroll
        for (int n = 0; n < 8; ++n) {
            float4 v;
            v.x = fmaxf(acc[n][0], 0.0f);
            v.y = fmaxf(acc[n][1], 0.0f);
            v.z = fmaxf(acc[n][2], 0.0f);
            v.w = fmaxf(acc[n][3], 0.0f);
            *reinterpret_cast<float4*>(orow + n * 16 + q * 4) = v;
        }
    }
}

// ---------------------------------------------------------------------------
extern "C" void kernel_launch(void* const* d_in, const int* in_sizes, int n_in,
                              void* d_out, int out_size, void* d_ws, size_t ws_size,
                              hipStream_t stream) {
    const float* feat = (const float*)d_in[0];
    const float* W    = (const float*)d_in[1];
    const int*   ei   = (const int*)d_in[2];
    float*       out  = (float*)d_out;

    const int E = in_sizes[2] / 2;           // 800000
    const int N = in_sizes[0] / D;           // 100000
    const int n2 = 2 * N;
    const int* src = ei;
    const int* dst = ei + E;

    // ws layout (4B units then 2B units, all 16B-aligned):
    // cnt[n2] | off[n2+4] | blk[256] | rankF[E] | rankB[E] | csr[2E] |
    // featb[N*D] u16 | Wb[128*384] u16 | meanb[2N*D] u16
    int* cnt   = (int*)d_ws;
    int* off   = cnt + n2;
    int* blk   = off + (n2 + 4);
    int* rankF = blk + 256;
    int* rankB = rankF + E;
    int* csr   = rankB + E;
    unsigned short* featb = (unsigned short*)(csr + 2 * E);
    unsigned short* Wb    = featb + (size_t)N * D;
    unsigned short* meanb = Wb + 128 * 384;

    const int NB = (n2 + CHUNK - 1) / CHUNK; // 196
    const int npr = (N + NXCD - 1) / NXCD;   // 12500 nodes per range
    const int n4f = N * D / 4;
    const int n4w = 128 * 384 / 4;
    const int ncb = 2048;                    // convert blocks

    hipMemsetAsync(cnt, 0, (size_t)n2 * sizeof(int), stream);

    convert_hist_kernel<<<ncb + 2048, 256, 0, stream>>>(
        feat, featb, n4f, W, Wb, n4w, src, dst, cnt, rankF, rankB, E, N, ncb);

    scan1_kernel<<<NB, 256, 0, stream>>>(cnt, blk, n2);
    scan3_kernel<<<NB, 256, 0, stream>>>(cnt, blk, off, n2, 2 * E, NB);
    scatter_ids_kernel<<<2048, 256, 0, stream>>>(src, dst, off, rankF, rankB,
                                                 csr, E, N, npr);

    const int gather_blocks = (n2 * 16 + 255) / 256;   // 16 lanes per segment
    gather_mean_kernel<<<gather_blocks, 256, 0, stream>>>(featb, off, csr, meanb, n2);

    mfma_gemm_kernel<<<(N + 127) / 128, 512, 0, stream>>>(featb, meanb, Wb, out, N);
}

// Round 17
// 222.218 us; speedup vs baseline: 1.0230x; 1.0230x over previous
//
#include <hip/hip_runtime.h>
#include <hip/hip_bf16.h>

#define D 128
#define CHUNK 1024   // elements per scan block (256 thr x 4)
#define NXCD 8

typedef __attribute__((ext_vector_type(8))) short bf16x8;
typedef __attribute__((ext_vector_type(4))) float f32x4;

// ---- bf16 helpers (bit-level, RNE via __float2bfloat16) --------------------
__device__ inline float bflo(unsigned u) { return __uint_as_float(u << 16); }
__device__ inline float bfhi(unsigned u) { return __uint_as_float(u & 0xffff0000u); }
__device__ inline unsigned short f2bf(float f) {
    __hip_bfloat16 h = __float2bfloat16(f);
    return *reinterpret_cast<unsigned short*>(&h);
}
__device__ inline unsigned pack2bf(float lo, float hi) {
    return (unsigned)f2bf(lo) | ((unsigned)f2bf(hi) << 16);
}

// ---------------------------------------------------------------------------
// convert: fp32->bf16, float8 per thread (2x float4 load -> 1x uint4 store =
// 16B/lane full-line store waves, G13). Also zeroes cnt[] (R15-proven fold;
// plain-store -> next-kernel atomic-RMW pattern).
// ---------------------------------------------------------------------------
__global__ __launch_bounds__(256) void convert_kernel(
    const float* __restrict__ feat, unsigned short* __restrict__ featb, int n8f,
    const float* __restrict__ W, unsigned short* __restrict__ Wb, int n8w,
    int* __restrict__ cnt, int n2)
{
    int i = blockIdx.x * blockDim.x + threadIdx.x;
    const int stride = gridDim.x * blockDim.x;
    const int n8 = n8f + n8w;
    for (int j = i; j < n8; j += stride) {
        const float* x; unsigned short* y; int k;
        if (j < n8f) { x = feat; y = featb; k = j; }
        else         { x = W;    y = Wb;    k = j - n8f; }
        const float* sp = x + (size_t)k * 8;
        float4 v0 = *reinterpret_cast<const float4*>(sp);
        float4 v1 = *reinterpret_cast<const float4*>(sp + 4);
        uint4 o;
        o.x = pack2bf(v0.x, v0.y);
        o.y = pack2bf(v0.z, v0.w);
        o.z = pack2bf(v1.x, v1.y);
        o.w = pack2bf(v1.z, v1.w);
        *reinterpret_cast<uint4*>(y + (size_t)k * 8) = o;
    }
    for (int z = i; z < n2; z += stride) cnt[z] = 0;
}

// ---------------------------------------------------------------------------
// hist+rank: one thread per edge; atomic RETURN value = edge's rank within
// its segment (R11/R12-proven; makes scatter atomic-free). Kept SEPARATE
// from convert: fusion falsified twice (R11 per-thread 101us, R16 block-
// split 90us = serial sum; atomics depress concurrent streaming BW).
// ---------------------------------------------------------------------------
__global__ __launch_bounds__(256) void hist_rank_kernel(
    const int* __restrict__ src, const int* __restrict__ dst,
    int* __restrict__ cnt, int* __restrict__ rankF, int* __restrict__ rankB,
    int E, int N)
{
    const int e = blockIdx.x * blockDim.x + threadIdx.x;
    if (e < E) {
        rankF[e] = atomicAdd(&cnt[dst[e]], 1);
        rankB[e] = atomicAdd(&cnt[N + src[e]], 1);
    }
}

// ---------------------------------------------------------------------------
// scan1: per-block (CHUNK=1024) sums of cnt into blk[] (R5-proven).
// ---------------------------------------------------------------------------
__global__ __launch_bounds__(256) void scan1_kernel(
    const int* __restrict__ cnt, int* __restrict__ blk, int n2)
{
    __shared__ int red[256];
    const int b = blockIdx.x, t = threadIdx.x;
    const int base = b * CHUNK + t * 4;
    int s = 0;
    if (base + 3 < n2) {
        int4 v = *reinterpret_cast<const int4*>(&cnt[base]);
        s = v.x + v.y + v.z + v.w;
    } else {
        for (int j = 0; j < 4; ++j) { int idx = base + j; if (idx < n2) s += cnt[idx]; }
    }
    red[t] = s; __syncthreads();
    for (int o = 128; o > 0; o >>= 1) { if (t < o) red[t] += red[t + o]; __syncthreads(); }
    if (t == 0) blk[b] = red[0];
}

// ---------------------------------------------------------------------------
// scan3 (scan2 folded in): self-scan of NB block sums in LDS, then chunk
// exclusive prefix -> off[] (IMMUTABLE afterwards). (R11/R12-proven.)
// ---------------------------------------------------------------------------
__global__ __launch_bounds__(256) void scan3_kernel(
    const int* __restrict__ cnt, const int* __restrict__ blk,
    int* __restrict__ off, int n2, int total, int NB)
{
    __shared__ int sh[256];
    __shared__ int bs[256];
    const int b = blockIdx.x, t = threadIdx.x;

    bs[t] = (t < NB) ? blk[t] : 0;
    __syncthreads();
    for (int o = 1; o < 256; o <<= 1) {
        int v = (t >= o) ? bs[t - o] : 0;
        __syncthreads();
        bs[t] += v;
        __syncthreads();
    }
    const int blkpref = (b > 0) ? bs[b - 1] : 0;

    const int base = b * CHUNK + t * 4;
    int v[4]; int s = 0;
    for (int j = 0; j < 4; ++j) { int idx = base + j; v[j] = (idx < n2) ? cnt[idx] : 0; s += v[j]; }
    sh[t] = s; __syncthreads();
    for (int o = 1; o < 256; o <<= 1) {
        int x = (t >= o) ? sh[t - o] : 0;
        __syncthreads();
        sh[t] += x;
        __syncthreads();
    }
    int excl = blkpref + ((t > 0) ? sh[t - 1] : 0);
    for (int j = 0; j < 4; ++j) {
        int idx = base + j;
        if (idx < n2) off[idx] = excl;
        excl += v[j];
    }
    if (b == 0 && t == 0) off[n2] = total;
}

// ---------------------------------------------------------------------------
// Scatter edge ids: ATOMIC-FREE (slot = off[seg] + rank), node-range
// partitioned for XCD write locality (R6/R11-proven).
// ---------------------------------------------------------------------------
__global__ __launch_bounds__(256) void scatter_ids_kernel(
    const int* __restrict__ src, const int* __restrict__ dst,
    const int* __restrict__ off,
    const int* __restrict__ rankF, const int* __restrict__ rankB,
    int* __restrict__ csr, int E, int N, int npr)
{
    const int grp = blockIdx.x & (NXCD - 1);
    const int bIn = blockIdx.x >> 3;
    const int nbk = gridDim.x >> 3;
    const int lo = grp * npr;
    const int hi = lo + npr;

    int i = bIn * 256 + threadIdx.x;
    const int stride = nbk * 256;
    for (int e = i; e < E; e += stride) {
        const int s = src[e];
        const int d = dst[e];
        if (d >= lo && d < hi) {
            csr[off[d] + rankF[e]] = s;
        }
        if (s >= lo && s < hi) {
            csr[off[N + s] + rankB[e]] = d;
        }
    }
}

// ---------------------------------------------------------------------------
// gather means (R12-proven form, plain csr loads — nt hurt in the R15 A/B:
// 87us/271MB vs 81us/259MB). 16 lanes per segment; lane l owns bf16 columns
// [8l, 8l+8). Bounds from IMMUTABLE off. Unroll-4.
// ---------------------------------------------------------------------------
__global__ __launch_bounds__(256) void gather_mean_kernel(
    const unsigned short* __restrict__ featb, const int* __restrict__ off,
    const int* __restrict__ csr, unsigned short* __restrict__ meanb, int n2)
{
    const int tid = blockIdx.x * 256 + threadIdx.x;
    const int seg = tid >> 4;
    const int l = tid & 15;
    if (seg >= n2) return;

    const int beg = off[seg], end = off[seg + 1];
    float a0=0,a1=0,a2=0,a3=0,a4=0,a5=0,a6=0,a7=0;

    int e = beg;
    for (; e + 3 < end; e += 4) {
        const int n0 = csr[e], n1 = csr[e + 1], n2i = csr[e + 2], n3 = csr[e + 3];
        const uint4 v0 = *reinterpret_cast<const uint4*>(featb + (size_t)n0 * D + l * 8);
        const uint4 v1 = *reinterpret_cast<const uint4*>(featb + (size_t)n1 * D + l * 8);
        const uint4 v2 = *reinterpret_cast<const uint4*>(featb + (size_t)n2i * D + l * 8);
        const uint4 v3 = *reinterpret_cast<const uint4*>(featb + (size_t)n3 * D + l * 8);
        a0 += (bflo(v0.x) + bflo(v1.x)) + (bflo(v2.x) + bflo(v3.x));
        a1 += (bfhi(v0.x) + bfhi(v1.x)) + (bfhi(v2.x) + bfhi(v3.x));
        a2 += (bflo(v0.y) + bflo(v1.y)) + (bflo(v2.y) + bflo(v3.y));
        a3 += (bfhi(v0.y) + bfhi(v1.y)) + (bfhi(v2.y) + bfhi(v3.y));
        a4 += (bflo(v0.z) + bflo(v1.z)) + (bflo(v2.z) + bflo(v3.z));
        a5 += (bfhi(v0.z) + bfhi(v1.z)) + (bfhi(v2.z) + bfhi(v3.z));
        a6 += (bflo(v0.w) + bflo(v1.w)) + (bflo(v2.w) + bflo(v3.w));
        a7 += (bfhi(v0.w) + bfhi(v1.w)) + (bfhi(v2.w) + bfhi(v3.w));
    }
    for (; e < end; ++e) {
        const int n0 = csr[e];
        const uint4 v0 = *reinterpret_cast<const uint4*>(featb + (size_t)n0 * D + l * 8);
        a0 += bflo(v0.x); a1 += bfhi(v0.x);
        a2 += bflo(v0.y); a3 += bfhi(v0.y);
        a4 += bflo(v0.z); a5 += bfhi(v0.z);
        a6 += bflo(v0.w); a7 += bfhi(v0.w);
    }

    const int deg = end - beg;
    const float inv = 1.0f / (float)((deg > 1) ? deg : 1);
    uint4 o;
    o.x = pack2bf(a0 * inv, a1 * inv);
    o.y = pack2bf(a2 * inv, a3 * inv);
    o.z = pack2bf(a4 * inv, a5 * inv);
    o.w = pack2bf(a6 * inv, a7 * inv);
    *reinterpret_cast<uint4*>(meanb + (size_t)seg * D + l * 8) = o;
}

// ---------------------------------------------------------------------------
// bf16 MFMA GEMM v3 (R9/R12-proven, byte-identical). 512 thr, 128 rows/blk,
// K=128 LDS slabs double-buffered (3 barriers), XOR-swizzled, 12 A-frags
// register-prefetched, operand-swapped mfma(w,h), float4 epilogue.
// ---------------------------------------------------------------------------
__global__ __launch_bounds__(512) void mfma_gemm_kernel(
    const unsigned short* __restrict__ featb,
    const unsigned short* __restrict__ meanb,
    const unsigned short* __restrict__ Wb,      // [128][384] bf16
    float* __restrict__ out, int N)
{
    __shared__ unsigned short wlds[2][128 * 128];   // 2 x 32KB, swizzled [col][k]

    const int t = threadIdx.x;
    const int wv = t >> 6;          // 0..7
    const int lane = t & 63;
    const int r = lane & 15;
    const int q = lane >> 4;        // 0..3

    const int row0 = blockIdx.x * 128 + wv * 16;
    const int row = row0 + r;
    const int rowc = (row < N) ? row : (N - 1);

    // ---- prefetch all 12 A-fragments ----
    const unsigned short* h0 = featb + (size_t)rowc * D;
    const unsigned short* h1 = meanb + (size_t)rowc * D;
    const unsigned short* h2 = meanb + ((size_t)N + rowc) * D;
    bf16x8 af[12];
#pragma unroll
    for (int kk = 0; kk < 4; ++kk) {
        af[kk]     = *reinterpret_cast<const bf16x8*>(h0 + kk * 32 + q * 8);
        af[4 + kk] = *reinterpret_cast<const bf16x8*>(h1 + kk * 32 + q * 8);
        af[8 + kk] = *reinterpret_cast<const bf16x8*>(h2 + kk * 32 + q * 8);
    }

    // ---- W staging: thread t owns col sc, 4 x 16B sub-chunks ----
    const int sc = t >> 2;          // 0..127
    const int sq = t & 3;           // 0..3
    const char* wsrc = reinterpret_cast<const char*>(Wb) + (size_t)sc * 768;
    const int swz = (sc & 7) << 4;

    f32x4 acc[8];
#pragma unroll
    for (int n = 0; n < 8; ++n) acc[n] = (f32x4){0.f, 0.f, 0.f, 0.f};

    // prologue: stage slab 0 into buf 0
    {
        uint4 st[4];
#pragma unroll
        for (int j = 0; j < 4; ++j)
            st[j] = *reinterpret_cast<const uint4*>(wsrc + j * 64 + sq * 16);
        char* wb0 = reinterpret_cast<char*>(&wlds[0][0]) + sc * 256;
#pragma unroll
        for (int j = 0; j < 4; ++j)
            *reinterpret_cast<uint4*>(wb0 + ((j * 64 + sq * 16) ^ swz)) = st[j];
    }
    __syncthreads();

#pragma unroll
    for (int ci = 0; ci < 3; ++ci) {
        uint4 nx[4];
        if (ci < 2) {
#pragma unroll
            for (int j = 0; j < 4; ++j)
                nx[j] = *reinterpret_cast<const uint4*>(
                    wsrc + (ci + 1) * 256 + j * 64 + sq * 16);
        }

        const char* wl = reinterpret_cast<const char*>(&wlds[ci & 1][0]);
#pragma unroll
        for (int kk = 0; kk < 4; ++kk) {
            const bf16x8 bh = af[ci * 4 + kk];
#pragma unroll
            for (int n = 0; n < 8; ++n) {
                const int c = n * 16 + r;
                const bf16x8 aw = *reinterpret_cast<const bf16x8*>(
                    wl + c * 256 + ((kk * 64 + q * 16) ^ ((c & 7) << 4)));
                acc[n] = __builtin_amdgcn_mfma_f32_16x16x32_bf16(aw, bh, acc[n], 0, 0, 0);
            }
        }

        if (ci < 2) {
            char* wbn = reinterpret_cast<char*>(&wlds[(ci + 1) & 1][0]) + sc * 256;
#pragma unroll
            for (int j = 0; j < 4; ++j)
                *reinterpret_cast<uint4*>(wbn + ((j * 64 + sq * 16) ^ swz)) = nx[j];
            __syncthreads();
        }
    }

    // epilogue: lane (q,r) holds out[row0+r][n*16 + q*4 + i], i=0..3
    if (row < N) {
        float* orow = out + (size_t)row * D;
#pragma unroll
        for (int n = 0; n < 8; ++n) {
            float4 v;
            v.x = fmaxf(acc[n][0], 0.0f);
            v.y = fmaxf(acc[n][1], 0.0f);
            v.z = fmaxf(acc[n][2], 0.0f);
            v.w = fmaxf(acc[n][3], 0.0f);
            *reinterpret_cast<float4*>(orow + n * 16 + q * 4) = v;
        }
    }
}

// ---------------------------------------------------------------------------
extern "C" void kernel_launch(void* const* d_in, const int* in_sizes, int n_in,
                              void* d_out, int out_size, void* d_ws, size_t ws_size,
                              hipStream_t stream) {
    const float* feat = (const float*)d_in[0];
    const float* W    = (const float*)d_in[1];
    const int*   ei   = (const int*)d_in[2];
    float*       out  = (float*)d_out;

    const int E = in_sizes[2] / 2;           // 800000
    const int N = in_sizes[0] / D;           // 100000
    const int n2 = 2 * N;
    const int* src = ei;
    const int* dst = ei + E;

    // ws layout (4B units then 2B units, all 16B-aligned):
    // cnt[n2] | off[n2+4] | blk[256] | rankF[E] | rankB[E] | csr[2E] |
    // featb[N*D] u16 | Wb[128*384] u16 | meanb[2N*D] u16
    int* cnt   = (int*)d_ws;
    int* off   = cnt + n2;
    int* blk   = off + (n2 + 4);
    int* rankF = blk + 256;
    int* rankB = rankF + E;
    int* csr   = rankB + E;
    unsigned short* featb = (unsigned short*)(csr + 2 * E);
    unsigned short* Wb    = featb + (size_t)N * D;
    unsigned short* meanb = Wb + 128 * 384;

    const int NB = (n2 + CHUNK - 1) / CHUNK; // 196
    const int npr = (N + NXCD - 1) / NXCD;   // 12500 nodes per range
    const int n8f = N * D / 8;               // 1.6M float8 groups
    const int n8w = 128 * 384 / 8;           // 6144 float8 groups

    // convert also zeroes cnt (no separate memset dispatch)
    convert_kernel<<<2048, 256, 0, stream>>>(feat, featb, n8f, W, Wb, n8w,
                                             cnt, n2);
    hist_rank_kernel<<<(E + 255) / 256, 256, 0, stream>>>(src, dst, cnt,
                                                          rankF, rankB, E, N);

    scan1_kernel<<<NB, 256, 0, stream>>>(cnt, blk, n2);
    scan3_kernel<<<NB, 256, 0, stream>>>(cnt, blk, off, n2, 2 * E, NB);
    scatter_ids_kernel<<<2048, 256, 0, stream>>>(src, dst, off, rankF, rankB,
                                                 csr, E, N, npr);

    const int gather_blocks = (n2 * 16 + 255) / 256;   // 16 lanes per segment
    gather_mean_kernel<<<gather_blocks, 256, 0, stream>>>(featb, off, csr, meanb, n2);

    mfma_gemm_kernel<<<(N + 127) / 128, 512, 0, stream>>>(featb, meanb, Wb, out, N);
}